// Round 14
// baseline (245.480 us; speedup 1.0000x reference)
//
#include <hip/hip_runtime.h>

// FDLT: out[b,m,o] = sum_i psiHat[b,m,i] * E[m][i][o]
//   E[m] = cm * X_parity(m) @ D[m]^T   (X = XFc even m, XFs odd m)
// BATCH=2048, B=128 (m), N=256 (i), O=128 (o)
//
// Kernel 1: e_kernel -> Bpack[m][t][cf][lane]·16B (MFMA fragment-packed).
// Kernel 2 (r14): r13's never-drain ring-2 pipeline with ONE change: A
//   staging via T14 reg-staging (global_load_dwordx4 -> VGPR -> ds_write)
//   instead of global_load_lds. Same 1KB-dense per-instr coalescing, same
//   LDS data placement (16B-unit XOR swizzle, applied at the LOAD address),
//   same barriers/stores. Tests whether the glds DMA path is the 4.2 TB/s
//   ceiling (m13's 6.3 TB/s was measured with register loads).

typedef __attribute__((ext_vector_type(8))) short short8;
typedef __attribute__((ext_vector_type(4))) float f32x4;

#define NBATCH 2048
#define NM 128
#define NI 256   // K dim (i / j)
#define NO 128   // output o dim
// Bpack per m: 8 t-steps x 8 cf x 64 lanes x 8 bf16 = 32768 shorts (64 KB)
#define BPACK_M 32768

#define NSLAB 8
#define SLABROWS 16
#define LDSBUF 16384   // bytes per slab buffer (16 rows x 1024 B)

__device__ __forceinline__ unsigned short f2bf(float f) {
  // round-to-nearest-even fp32 -> bf16
  unsigned int u = __builtin_bit_cast(unsigned int, f);
  u += 0x7FFFu + ((u >> 16) & 1u);
  return (unsigned short)(u >> 16);
}

__device__ __forceinline__ short8 cvt8(float4 a, float4 b, float s) {
  short8 v;
  v[0] = (short)f2bf(s * a.x); v[1] = (short)f2bf(s * a.y);
  v[2] = (short)f2bf(s * a.z); v[3] = (short)f2bf(s * a.w);
  v[4] = (short)f2bf(s * b.x); v[5] = (short)f2bf(s * b.y);
  v[6] = (short)f2bf(s * b.z); v[7] = (short)f2bf(s * b.w);
  return v;
}

// ---------------- Kernel 1: E precompute -> fragment-packed Bpack ----------
__global__ __launch_bounds__(256) void e_kernel(
    const float* __restrict__ XFc, const float* __restrict__ XFs,
    const float* __restrict__ D, const float* __restrict__ cmp,
    unsigned short* __restrict__ Bpack)
{
  const int m = blockIdx.x >> 1;
  const int ihalf = blockIdx.x & 1;
  const int tid = threadIdx.x;
  const int lane = tid & 63;
  const int w = tid >> 6;
  const int lr = lane & 15;   // frag row (A) / col (B)
  const int lg = lane >> 4;   // k group
  const float cm = cmp[0];
  const float* __restrict__ Xp = (m & 1) ? XFs : XFc;
  const float* __restrict__ Dm = D + (size_t)m * (NO * NI);
  const int i0 = ihalf * 128 + w * 32;   // multiple of 32

  f32x4 acc[2][8];
#pragma unroll
  for (int a = 0; a < 2; a++)
#pragma unroll
    for (int b = 0; b < 8; b++) acc[a][b] = (f32x4)0.f;

  for (int kk = 0; kk < NI; kk += 32) {
    const int kb = kk + lg * 8;
    short8 af[2];
#pragma unroll
    for (int rf = 0; rf < 2; rf++) {
      const float* ap = Xp + (size_t)(i0 + rf * 16 + lr) * NI + kb;
      float4 x0 = *(const float4*)ap;
      float4 x1 = *(const float4*)(ap + 4);
      af[rf] = cvt8(x0, x1, cm);
    }
    short8 bf[8];
#pragma unroll
    for (int cf = 0; cf < 8; cf++) {
      const float* bp = Dm + (size_t)(cf * 16 + lr) * NI + kb;
      float4 x0 = *(const float4*)bp;
      float4 x1 = *(const float4*)(bp + 4);
      bf[cf] = cvt8(x0, x1, 1.0f);
    }
#pragma unroll
    for (int rf = 0; rf < 2; rf++)
#pragma unroll
      for (int cf = 0; cf < 8; cf++)
        acc[rf][cf] = __builtin_amdgcn_mfma_f32_16x16x32_bf16(
            af[rf], bf[cf], acc[rf][cf], 0, 0, 0);
  }

  // acc C/D: o = cf*16 + lr, i = i0 + rf*16 + lg*4 + reg.
  // Consumer layout: lane L of (t,cf) holds E[i = t*32 + (L>>4)*8 + j][o =
  // cf*16 + (L&15)], j=0..7. Our 4 regs are half of one 8-run:
  //   t = (i0 + rf*16) >> 5, L = ((2*rf + (lg>>1)) & 3)*16 + lr, j0 = (lg&1)*4
  unsigned short* Bm = Bpack + (size_t)m * BPACK_M;
#pragma unroll
  for (int rf = 0; rf < 2; rf++) {
    const int t = (i0 + rf * 16) >> 5;
    const int L = ((2 * rf + (lg >> 1)) & 3) * 16 + lr;
#pragma unroll
    for (int cf = 0; cf < 8; cf++) {
      ushort4 pk;
      pk.x = f2bf(acc[rf][cf][0]);
      pk.y = f2bf(acc[rf][cf][1]);
      pk.z = f2bf(acc[rf][cf][2]);
      pk.w = f2bf(acc[rf][cf][3]);
      *(ushort4*)(Bm + (size_t)(t * 8 + cf) * 512 + L * 8 + (lg & 1) * 4) = pk;
    }
  }
}

// ---------------- Kernel 2: main GEMM, ring-2 reg-staged pipeline ----------
// grid: (NM fast, NBATCH/128) = (128, 16). 256 threads = 4 waves.
// Block: one m, rows bbase..+127 as 8 slabs of 16; wave w owns o-quarter
// cf = {2w, 2w+1}. LDS: ring of 2 x [16 rows][1024 B]. Data placement
// identical to r13: phys 16B-unit p of row r holds logical unit p^(r&15)
// (swizzle applied at the LOAD address; ds_write is linear lane*16).
#define SB __builtin_amdgcn_sched_barrier(0)

__global__ __launch_bounds__(256, 4) void fdlt_main(
    const float* __restrict__ psiHat,
    const unsigned short* __restrict__ Bpack,
    float* __restrict__ out)
{
  __shared__ float As_f[2 * SLABROWS * 256];   // 32 KB
  const int m = blockIdx.x;
  const int tid = threadIdx.x;
  const int lane = tid & 63;
  const int w = tid >> 6;
  const int bbase = blockIdx.y * (NSLAB * SLABROWS);
  const int lr = lane & 15;
  const int lg = lane >> 4;
  const int cfbase = w * 2;
  char* As = (char*)As_f;

  const unsigned short* __restrict__ Bm = Bpack + (size_t)m * BPACK_M;

  // ---- B resident for the whole block: 16 x short8 = 64 VGPR ----
  short8 ball[8][2];
#pragma unroll
  for (int t = 0; t < 8; t++)
#pragma unroll
    for (int j = 0; j < 2; j++)
      ball[t][j] = *(const short8*)(
          Bm + (size_t)(t * 8 + cfbase + j) * 512 + lane * 8);

  // ---- T14 reg-staging: 4 x dwordx4 per wave, each instr = one dense
  // 1KB psiHat row (lane l covers logical 16B-unit l ^ (r&15)) ----
  float4 xaA[4], xaB[4];
  auto LOADR = [&](int s, float4* xa) {
#pragma unroll
    for (int j = 0; j < 4; j++) {
      const int r = j * 4 + w;
      const int fofs = ((lane ^ (r & 15)) << 2);
      xa[j] = *(const float4*)(
          psiHat + ((size_t)(bbase + s * SLABROWS + r) * NM + m) * NI + fofs);
    }
  };
  // linear ds_write: phys unit lane of row r <- xa[j] (logical lane^(r&15))
  auto WRITELDS = [&](int s, const float4* xa) {
#pragma unroll
    for (int j = 0; j < 4; j++) {
      const int r = j * 4 + w;
      *(float4*)(As + (s & 1) * LDSBUF + r * 1024 + lane * 16) = xa[j];
    }
  };

  f32x4 acc[2];

  // ---- prologue ----
  LOADR(0, xaA);
  LOADR(1, xaB);
  // ledger: ball[16], loads0[4], loads1[4] -> keep 4 = loads(1)
  asm volatile("s_waitcnt vmcnt(4)" ::: "memory");
  SB;
  WRITELDS(0, xaA);
  asm volatile("s_waitcnt lgkmcnt(0)" ::: "memory");
  SB;
  __builtin_amdgcn_s_barrier();   // buf0 published
  SB;

#pragma unroll
  for (int s = 0; s < NSLAB; s++) {
    // ---- issue loads(s+2) into the reg set consumed last slab ----
    if (s + 2 < NSLAB) LOADR(s + 2, (s & 1) ? xaB : xaA);

    // ---- compute slab s from buf (s&1); zero VMEM in this phase ----
    const char* Arow = As + (s & 1) * LDSBUF + lr * 1024;
#pragma unroll
    for (int j = 0; j < 2; j++) acc[j] = (f32x4)0.f;
#pragma unroll
    for (int t = 0; t < 8; t++) {
      const int p0 = ((((t * 4 + lg) << 1) ^ lr) << 4);
      float4 x0 = *(const float4*)(Arow + p0);
      float4 x1 = *(const float4*)(Arow + (p0 ^ 16));
      short8 af = cvt8(x0, x1, 1.0f);
#pragma unroll
      for (int j = 0; j < 2; j++)
        acc[j] = __builtin_amdgcn_mfma_f32_16x16x32_bf16(
            af, ball[t][j], acc[j], 0, 0, 0);
    }

    // ---- store slab s: 8 dwords/lane (fire-and-forget) ----
#pragma unroll
    for (int j = 0; j < 2; j++) {
      const int o = (cfbase + j) * 16 + lr;
#pragma unroll
      for (int r = 0; r < 4; r++) {
        const int b = bbase + s * SLABROWS + lg * 4 + r;
        out[((size_t)b * NM + m) * NO + o] = acc[j][r];
      }
    }
    SB;

    // ---- maintenance: retire loads(s+1), ds_write them, publish ----
    if (s + 1 < NSLAB) {
      // FIFO ledger oldest->youngest at this point:
      //   s=0:    loads(1)[4], stores(0)[8], loads(2)[4]            -> keep 12
      //   steady: loads(s+1)[4], stores(s-1)[8], loads(s+2)[4],
      //           stores(s)[8]                                      -> keep 20
      //   s=NSLAB-2 (no loads(s+2)): loads(s+1)[4], stores(s-1)[8],
      //           stores(s)[8]                                      -> keep 16
      if (s == 0)
        asm volatile("s_waitcnt vmcnt(12)" ::: "memory");
      else if (s + 2 < NSLAB)
        asm volatile("s_waitcnt vmcnt(20)" ::: "memory");
      else
        asm volatile("s_waitcnt vmcnt(16)" ::: "memory");
      SB;
      WRITELDS(s + 1, (s & 1) ? xaA : xaB);   // target buf((s+1)&1): free
                                              // since slab s-1's barrier
      asm volatile("s_waitcnt lgkmcnt(0)" ::: "memory");
      SB;
      __builtin_amdgcn_s_barrier();           // buf(s+1) published
      SB;
    }
  }
}

extern "C" void kernel_launch(void* const* d_in, const int* in_sizes, int n_in,
                              void* d_out, int out_size, void* d_ws, size_t ws_size,
                              hipStream_t stream) {
  const float* psiHat = (const float*)d_in[0];
  const float* cm     = (const float*)d_in[1];
  const float* XFc    = (const float*)d_in[2];
  const float* XFs    = (const float*)d_in[3];
  const float* D      = (const float*)d_in[4];
  float* out = (float*)d_out;
  unsigned short* Bpack = (unsigned short*)d_ws;  // 128*32768*2 = 8.39 MB

  e_kernel<<<256, 256, 0, stream>>>(XFc, XFs, D, cm, Bpack);
  fdlt_main<<<dim3(NM, NBATCH / (NSLAB * SLABROWS)), 256, 0, stream>>>(
      psiHat, Bpack, out);
}

// Round 15
// 106.344 us; speedup vs baseline: 2.3084x; 2.3084x over previous
//
#include <hip/hip_runtime.h>

// FDLT: out[b,m,o] = sum_i psiHat[b,m,i] * E[m][i][o]
//   E[m] = cm * X_parity(m) @ D[m]^T   (X = XFc even m, XFs odd m)
// BATCH=2048, B=128 (m), N=256 (i), O=128 (o)
//
// Kernel 1: e_kernel -> Bpack[m][t][cf][lane]·16B (MFMA fragment-packed).
// Kernel 2 (r15): r13's ring-2 never-drain pipeline + TRANSPOSED STORE
//   EPILOGUE. r1-r13 all stored per-lane scalars: each instr = 4x 64B
//   segments at 64KB stride (DRAM page thrash on the write stream) — the
//   one stream never varied across 13 structures stuck at ~4.2 TB/s.
//   Now: acc -> LDS OutBuf (8KB, XOR-swizzled) -> barrier ->
//   ds_read_b128 + global_store_dwordx4 = two dense 512B row-segments
//   per instr (full 128B lines, 8x coarser page touches).

typedef __attribute__((ext_vector_type(8))) short short8;
typedef __attribute__((ext_vector_type(4))) float f32x4;

#define NBATCH 2048
#define NM 128
#define NI 256   // K dim (i / j)
#define NO 128   // output o dim
// Bpack per m: 8 t-steps x 8 cf x 64 lanes x 8 bf16 = 32768 shorts (64 KB)
#define BPACK_M 32768

#define NSLAB 8
#define SLABROWS 16
#define LDSBUF 16384   // bytes per A slab buffer (16 rows x 1024 B)

#define GLB(p) ((const __attribute__((address_space(1))) void*)(p))
#define LDS(p) ((__attribute__((address_space(3))) void*)(p))

__device__ __forceinline__ unsigned short f2bf(float f) {
  // round-to-nearest-even fp32 -> bf16
  unsigned int u = __builtin_bit_cast(unsigned int, f);
  u += 0x7FFFu + ((u >> 16) & 1u);
  return (unsigned short)(u >> 16);
}

__device__ __forceinline__ short8 cvt8(float4 a, float4 b, float s) {
  short8 v;
  v[0] = (short)f2bf(s * a.x); v[1] = (short)f2bf(s * a.y);
  v[2] = (short)f2bf(s * a.z); v[3] = (short)f2bf(s * a.w);
  v[4] = (short)f2bf(s * b.x); v[5] = (short)f2bf(s * b.y);
  v[6] = (short)f2bf(s * b.z); v[7] = (short)f2bf(s * b.w);
  return v;
}

// ---------------- Kernel 1: E precompute -> fragment-packed Bpack ----------
__global__ __launch_bounds__(256) void e_kernel(
    const float* __restrict__ XFc, const float* __restrict__ XFs,
    const float* __restrict__ D, const float* __restrict__ cmp,
    unsigned short* __restrict__ Bpack)
{
  const int m = blockIdx.x >> 1;
  const int ihalf = blockIdx.x & 1;
  const int tid = threadIdx.x;
  const int lane = tid & 63;
  const int w = tid >> 6;
  const int lr = lane & 15;   // frag row (A) / col (B)
  const int lg = lane >> 4;   // k group
  const float cm = cmp[0];
  const float* __restrict__ Xp = (m & 1) ? XFs : XFc;
  const float* __restrict__ Dm = D + (size_t)m * (NO * NI);
  const int i0 = ihalf * 128 + w * 32;   // multiple of 32

  f32x4 acc[2][8];
#pragma unroll
  for (int a = 0; a < 2; a++)
#pragma unroll
    for (int b = 0; b < 8; b++) acc[a][b] = (f32x4)0.f;

  for (int kk = 0; kk < NI; kk += 32) {
    const int kb = kk + lg * 8;
    short8 af[2];
#pragma unroll
    for (int rf = 0; rf < 2; rf++) {
      const float* ap = Xp + (size_t)(i0 + rf * 16 + lr) * NI + kb;
      float4 x0 = *(const float4*)ap;
      float4 x1 = *(const float4*)(ap + 4);
      af[rf] = cvt8(x0, x1, cm);
    }
    short8 bf[8];
#pragma unroll
    for (int cf = 0; cf < 8; cf++) {
      const float* bp = Dm + (size_t)(cf * 16 + lr) * NI + kb;
      float4 x0 = *(const float4*)bp;
      float4 x1 = *(const float4*)(bp + 4);
      bf[cf] = cvt8(x0, x1, 1.0f);
    }
#pragma unroll
    for (int rf = 0; rf < 2; rf++)
#pragma unroll
      for (int cf = 0; cf < 8; cf++)
        acc[rf][cf] = __builtin_amdgcn_mfma_f32_16x16x32_bf16(
            af[rf], bf[cf], acc[rf][cf], 0, 0, 0);
  }

  // acc C/D: o = cf*16 + lr, i = i0 + rf*16 + lg*4 + reg.
  // Consumer layout: lane L of (t,cf) holds E[i = t*32 + (L>>4)*8 + j][o =
  // cf*16 + (L&15)], j=0..7. Our 4 regs are half of one 8-run:
  //   t = (i0 + rf*16) >> 5, L = ((2*rf + (lg>>1)) & 3)*16 + lr, j0 = (lg&1)*4
  unsigned short* Bm = Bpack + (size_t)m * BPACK_M;
#pragma unroll
  for (int rf = 0; rf < 2; rf++) {
    const int t = (i0 + rf * 16) >> 5;
    const int L = ((2 * rf + (lg >> 1)) & 3) * 16 + lr;
#pragma unroll
    for (int cf = 0; cf < 8; cf++) {
      ushort4 pk;
      pk.x = f2bf(acc[rf][cf][0]);
      pk.y = f2bf(acc[rf][cf][1]);
      pk.z = f2bf(acc[rf][cf][2]);
      pk.w = f2bf(acc[rf][cf][3]);
      *(ushort4*)(Bm + (size_t)(t * 8 + cf) * 512 + L * 8 + (lg & 1) * 4) = pk;
    }
  }
}

// ---------------- Kernel 2: main GEMM, ring-2 + transposed epilogue --------
// grid: (NM fast, NBATCH/128) = (128, 16). 256 threads = 4 waves.
// Block: one m, rows bbase..+127 as 8 slabs of 16; wave w owns o-quarter
// cf = {2w, 2w+1}. A-LDS: ring of 2 x [16 rows][1024 B], 16B-unit XOR
// swizzle p = u ^ (r&15) on glds SOURCE, undone on ds_read (r13-verified).
// OutBuf: [16 rows][512 B], 16B-unit XOR swizzle p = u ^ (row&7).
#define SB __builtin_amdgcn_sched_barrier(0)

__global__ __launch_bounds__(256, 4) void fdlt_main(
    const float* __restrict__ psiHat,
    const unsigned short* __restrict__ Bpack,
    float* __restrict__ out)
{
  __shared__ float As_f[2 * SLABROWS * 256];   // 32 KB
  __shared__ float Ob_f[SLABROWS * 128];       //  8 KB -> 40 KB total
  const int m = blockIdx.x;
  const int tid = threadIdx.x;
  const int lane = tid & 63;
  const int w = tid >> 6;
  const int bbase = blockIdx.y * (NSLAB * SLABROWS);
  const int lr = lane & 15;
  const int lg = lane >> 4;
  const int cfbase = w * 2;
  char* As = (char*)As_f;
  char* Ob = (char*)Ob_f;

  const unsigned short* __restrict__ Bm = Bpack + (size_t)m * BPACK_M;

  // ---- B resident for the whole block: 16 x short8 = 64 VGPR ----
  short8 ball[8][2];
#pragma unroll
  for (int t = 0; t < 8; t++)
#pragma unroll
    for (int j = 0; j < 2; j++)
      ball[t][j] = *(const short8*)(
          Bm + (size_t)(t * 8 + cfbase + j) * 512 + lane * 8);

  // ---- staging: 4 glds/wave, each one full 1KB contiguous psiHat row ----
  auto STAGE = [&](int s) {
#pragma unroll
    for (int j = 0; j < 4; j++) {
      const int r = j * 4 + w;
      const int fofs = ((lane ^ (r & 15)) << 2);
      const float* src =
          psiHat + ((size_t)(bbase + s * SLABROWS + r) * NM + m) * NI + fofs;
      __builtin_amdgcn_global_load_lds(GLB(src),
                                       LDS(As + (s & 1) * LDSBUF + r * 1024),
                                       16, 0, 0);
    }
  };

  f32x4 acc[2];

  STAGE(0);
  STAGE(1);
  // FIFO: ball[16], stage0[4], stage1[4] -> keep 4 = stage(1)
  asm volatile("s_waitcnt vmcnt(4)" ::: "memory");
  SB;
  __builtin_amdgcn_s_barrier();   // all waves' stage(0) visible
  SB;

  for (int s = 0; s < NSLAB; s++) {
    // ---- compute slab s from A-buf (s&1); zero VMEM in this phase ----
    const char* Arow = As + (s & 1) * LDSBUF + lr * 1024;
#pragma unroll
    for (int j = 0; j < 2; j++) acc[j] = (f32x4)0.f;
#pragma unroll
    for (int t = 0; t < 8; t++) {
      const int p0 = ((((t * 4 + lg) << 1) ^ lr) << 4);
      float4 x0 = *(const float4*)(Arow + p0);
      float4 x1 = *(const float4*)(Arow + (p0 ^ 16));
      short8 af = cvt8(x0, x1, 1.0f);
#pragma unroll
      for (int j = 0; j < 2; j++)
        acc[j] = __builtin_amdgcn_mfma_f32_16x16x32_bf16(
            af, ball[t][j], acc[j], 0, 0, 0);
    }

    // ---- epilogue stage 1: acc -> OutBuf (LDS), XOR-swizzled units ----
    // OutBuf row = lg*4 + r, o = (cfbase+j)*16 + lr; unit u = o>>2,
    // phys p = u ^ (row&7); ~2-way write conflicts (free).
#pragma unroll
    for (int j = 0; j < 2; j++) {
      const int u = (cfbase + j) * 4 + (lr >> 2);
#pragma unroll
      for (int r = 0; r < 4; r++) {
        const int row = lg * 4 + r;
        const int p = u ^ (row & 7);
        *(float*)(Ob + row * 512 + p * 16 + (lr & 3) * 4) = acc[j][r];
      }
    }
    asm volatile("s_waitcnt lgkmcnt(0)" ::: "memory");
    SB;
    __builtin_amdgcn_s_barrier();   // OutBuf published; A-buf(s&1) free
    SB;

    // ---- prefetch next A slab into the freed buffer ----
    if (s + 2 < NSLAB) STAGE(s + 2);

    // ---- epilogue stage 2: OutBuf -> global, 2x 512B-dense rows/instr ----
#pragma unroll
    for (int i = 0; i < 2; i++) {
      const int c = i * 256 + tid;
      const int row = c >> 5;          // 0..15
      const int u = c & 31;            // 16B unit within 512B row
      const int p = u ^ (row & 7);
      float4 v = *(const float4*)(Ob + row * 512 + p * 16);
      *(float4*)(&out[((size_t)(bbase + s * SLABROWS + row) * NM + m) * NO +
                      u * 4]) = v;
    }
    SB;

    // ---- pipeline maintenance: counted vmcnt BEFORE barrier2 ----
    // FIFO ledger oldest->youngest at the vmcnt:
    //   steady: stage(s+1)[4], stores(s-1)[2], stage(s+2)[4], stores(s)[2]
    //           -> keep 6 (retires stage(s+1) + older)
    //   s+2==NSLAB: stage(s+1)[4], stores(s-1)[2], stores(s)[2] -> keep 2
    if (s + 1 < NSLAB) {
      if (s + 2 < NSLAB)
        asm volatile("s_waitcnt vmcnt(6)" ::: "memory");
      else
        asm volatile("s_waitcnt vmcnt(2)" ::: "memory");
      SB;
      __builtin_amdgcn_s_barrier();   // stage(s+1) visible; OutBuf reusable
      SB;
    }
  }
}

extern "C" void kernel_launch(void* const* d_in, const int* in_sizes, int n_in,
                              void* d_out, int out_size, void* d_ws, size_t ws_size,
                              hipStream_t stream) {
  const float* psiHat = (const float*)d_in[0];
  const float* cm     = (const float*)d_in[1];
  const float* XFc    = (const float*)d_in[2];
  const float* XFs    = (const float*)d_in[3];
  const float* D      = (const float*)d_in[4];
  float* out = (float*)d_out;
  unsigned short* Bpack = (unsigned short*)d_ws;  // 128*32768*2 = 8.39 MB

  e_kernel<<<256, 256, 0, stream>>>(XFc, XFs, D, cm, Bpack);
  fdlt_main<<<dim3(NM, NBATCH / (NSLAB * SLABROWS)), 256, 0, stream>>>(
      psiHat, Bpack, out);
}